// Round 1
// baseline (205.012 us; speedup 1.0000x reference)
//
#include <hip/hip_runtime.h>

// VecLocal2d: locally-connected conv2d, unshared 3x3 weights per output pixel.
// x:    [160][32][32][32]  (bk, c, h, w)        fp32
// w:    [32][32][64][32][3][3] (i, j, o, c, kh, kw) fp32
// bias: [10][64][32][32]   (k, o, i, j)         fp32
// out:  [160][64][32][32]  (bk, o, i, j)        fp32, bk = b*10 + k
//
// Block = (i, j-tile of 8, o-tile of 8). Weight slice (8j x 8o x 288 fp32)
// staged ONCE into LDS as bf16 (36 KB -> 4 blocks/CU), reused by all 160 bk.
// Threads 256 = j_sub(8) x o_q(2; 4 o's each) x bkg(16; 10 bk each).
// acc[4][10]: each x load feeds 4 FMAs.

#define C_INN 32
#define C_OUTT 64
#define HW 32
#define FDIM 288        // C_IN * 9
#define JT 8
#define OT 8
#define WPAD 289        // LDS row pad: 289 % 32 == 1 -> <=2-way bank aliasing

static __device__ inline unsigned short f2bf(float f) {
    unsigned u = __float_as_uint(f);
    u += 0x7FFFu + ((u >> 16) & 1u);   // round-to-nearest-even
    return (unsigned short)(u >> 16);
}
static __device__ inline float bf2f(unsigned short h) {
    return __uint_as_float(((unsigned)h) << 16);
}

__global__ __launch_bounds__(256) void local2d_fp32_kernel(
    const float* __restrict__ x,
    const float* __restrict__ w,
    const float* __restrict__ bias,
    float* __restrict__ out)
{
    // row = o_sub*8 + j_sub  (o-major so simultaneous reads spread banks)
    __shared__ unsigned short Wl[OT * JT][WPAD];

    const int bidx = blockIdx.x;          // 1024 = i(32) * jt(4) * ot(8)
    const int i  = bidx >> 5;
    const int jt = (bidx >> 3) & 3;
    const int ot = bidx & 7;
    const int j0 = jt * JT;
    const int o0 = ot * OT;

    const int tid = threadIdx.x;

    // ---- stage weight tile: 8j x 8o x 288 fp32 -> bf16 LDS ----
    // global: w[((i*32 + j)*64 + o)*288 + f], contiguous per (j,o) over f.
    for (int c = tid; c < JT * OT * (FDIM / 4); c += 256) {
        const int j_sub = c / (OT * (FDIM / 4));               // /576
        const int rem   = c - j_sub * (OT * (FDIM / 4));
        const int o_sub = rem / (FDIM / 4);                    // /72
        const int f4    = rem - o_sub * (FDIM / 4);
        const float4 v = *reinterpret_cast<const float4*>(
            w + ((size_t)((i * 32 + j0 + j_sub) * 64 + (o0 + o_sub))) * FDIM + f4 * 4);
        unsigned short* dst = &Wl[o_sub * JT + j_sub][f4 * 4];
        dst[0] = f2bf(v.x); dst[1] = f2bf(v.y);
        dst[2] = f2bf(v.z); dst[3] = f2bf(v.w);
    }
    __syncthreads();

    const int j_sub = tid & 7;
    const int o_q   = (tid >> 3) & 1;
    const int bkg   = tid >> 4;           // 0..15, 10 bk each
    const int j     = j0 + j_sub;

    float acc[4][10];
#pragma unroll
    for (int oo = 0; oo < 4; ++oo)
#pragma unroll
        for (int bb = 0; bb < 10; ++bb) acc[oo][bb] = 0.f;

    const float* xb = x + (size_t)(bkg * 10) * (C_INN * HW * HW);

    for (int c = 0; c < C_INN; ++c) {
#pragma unroll
        for (int kh = 0; kh < 3; ++kh) {
            const int ih = i - 1 + kh;
            if ((unsigned)ih >= (unsigned)HW) continue;   // wave-uniform skip
            const float* xpr = xb + c * (HW * HW) + ih * HW;
#pragma unroll
            for (int kw = 0; kw < 3; ++kw) {
                const int jw = j - 1 + kw;                // per-lane
                const bool jv = (unsigned)jw < (unsigned)HW;
                const int f = (c * 3 + kh) * 3 + kw;
                float wr[4];
#pragma unroll
                for (int oo = 0; oo < 4; ++oo)
                    wr[oo] = bf2f(Wl[(o_q * 4 + oo) * JT + j_sub][f]);
                const float* xp = xpr + jw;
#pragma unroll
                for (int bb = 0; bb < 10; ++bb) {
                    const float xv = jv ? xp[(size_t)bb * (C_INN * HW * HW)] : 0.f;
#pragma unroll
                    for (int oo = 0; oo < 4; ++oo)
                        acc[oo][bb] = fmaf(wr[oo], xv, acc[oo][bb]);
                }
            }
        }
    }

    // ---- epilogue: add bias, store (j lanes -> 32B-contiguous stores) ----
    const int pix = i * HW + j;
#pragma unroll
    for (int bb = 0; bb < 10; ++bb) {
        const int bk = bkg * 10 + bb;     // k = bk % 10 == bb
#pragma unroll
        for (int oo = 0; oo < 4; ++oo) {
            const int o = o0 + o_q * 4 + oo;
            out[((size_t)(bk * C_OUTT + o) << 10) + pix] =
                acc[oo][bb] + bias[((size_t)(bb * C_OUTT + o) << 10) + pix];
        }
    }
}

extern "C" void kernel_launch(void* const* d_in, const int* in_sizes, int n_in,
                              void* d_out, int out_size, void* d_ws, size_t ws_size,
                              hipStream_t stream) {
    const float* x    = (const float*)d_in[0];
    const float* w    = (const float*)d_in[1];
    const float* bias = (const float*)d_in[2];
    float* out        = (float*)d_out;

    dim3 grid(1024);   // i(32) * jt(4) * ot(8)
    dim3 block(256);
    hipLaunchKernelGGL(local2d_fp32_kernel, grid, block, 0, stream, x, w, bias, out);
}